// Round 6
// baseline (2236.304 us; speedup 1.0000x reference)
//
#include <hip/hip_runtime.h>
#include <stdint.h>

// SPINN thin-stack TreeLSTM, MI355X, round 12: PARTIAL-SHIPPING pair scheme.
// Pair (g2) = blocks (2g2, 2g2+1); block sl owns 64 H-dims (320 gate cols).
// The ONLY cross-block-fresh value was hr-partner = partner h(t-1). Now the
// OWNER of that h computes the rank-64 gate update against the PARTNER's 320
// cols (W_ship 64x320 in LDS, quad-XOR-swizzled) and ships 2x320 self-tagged
// (f32,t+1) words at the START of its P1(t); receiver adds them in its P2(t)
// cell. Send->consume distance = one full GEMM phase -> flight hidden, poll
// hits first try. P1 has ZERO cross-block dependency. Local GEMM = 256 K-rows
// (label 64 | hl-own 64 | hl-partner 64 | hr-own 64), W_reg 160 f32/thread.
// hl-partner li==t-1 reads partner h(t-1) from a tagged h-ring (published one
// full step earlier at partner P2(t-1) -> short spin). Rings 4-deep (skew
// bound <=2 by the partial dependency chain). rec/cown unchanged (old reads).

#define D     512
#define HD    128
#define LD    64
#define NTHR  512
#define GPR   328   // gp row stride (floats): 256 quad cols + 64 u cols + pad

typedef unsigned long long u64t;

__device__ __forceinline__ float sigf(float x){ return 1.0f/(1.0f+__expf(-x)); }
__device__ __forceinline__ float tanh_(float x){ return 1.0f-2.0f/(__expf(2.0f*x)+1.0f); }
__device__ __forceinline__ u64t gld64(const float* p){
  return __hip_atomic_load((const u64t*)p, __ATOMIC_RELAXED, __HIP_MEMORY_SCOPE_AGENT);
}
__device__ __forceinline__ u64t gld64r(const u64t* p){
  return __hip_atomic_load(p, __ATOMIC_RELAXED, __HIP_MEMORY_SCOPE_AGENT);
}
__device__ __forceinline__ void gst32(float* p, float v){
  __hip_atomic_store(p, v, __ATOMIC_RELAXED, __HIP_MEMORY_SCOPE_AGENT);
}
__device__ __forceinline__ void gst64r(u64t* p, u64t v){
  __hip_atomic_store(p, v, __ATOMIC_RELAXED, __HIP_MEMORY_SCOPE_AGENT);
}
__device__ __forceinline__ u64t packw(float v, unsigned tg){
  return ((u64t)tg << 32) | (u64t)__float_as_uint(v);
}
__device__ __forceinline__ float loww(u64t w){
  return __uint_as_float((unsigned)(w & 0xffffffffu));
}

__global__ __launch_bounds__(NTHR,2) void spinn_kernel(
    const int* __restrict__ trans, const int* __restrict__ labels,
    const float* __restrict__ emb, const float* __restrict__ W,
    const float* __restrict__ bias, const float* __restrict__ leaf,
    float* __restrict__ out, u64t* __restrict__ Pring,
    u64t* __restrict__ hring, float* __restrict__ rec,
    float* __restrict__ cown)
{
  const int bid = blockIdx.x;
  const int g2 = bid>>1, sl = bid&1, ps = sl^1;
  const int gb0 = g2*2;
  const int tid = threadIdx.x;
  const int kg = tid>>6, lane = tid&63;
  const int cq = lane;

  // xs K-layout (block-local): [0,64) label | [64,128) hl-own |
  // [128,192) hl-partner | [192,256) hr-own.  (hr-partner is SHIPPED.)
  __shared__ __align__(16) float  xs[2][2][256];
  __shared__ __align__(16) float4 wsq[320][16];    // W_ship^T, quad-swizzled
  __shared__ __align__(16) float  gpq[16][GPR];
  __shared__ float bsl[320];
  __shared__ float lshd[HD];
  __shared__ float clb[2][2][64];
  __shared__ uint8_t mS[D][2];
  __shared__ short liA[D][2];
  __shared__ unsigned short stk_[2][D];

  // --- W_reg: 32 local K-rows/wave x (4 quad cols + 1 u col) = 160 f32 ---
  float4 wr4[32]; float wr1[32];
  {
    const int gq = (cq>>4)*128 + sl*64 + ((cq*4)&63);  // own quad cols
    const int gu = 512 + sl*64 + cq;                   // own u col
#pragma unroll
    for (int j=0;j<32;++j){
      const int k = kg*32 + j;
      int R;
      if      (k < 64)  R = k;                          // label
      else if (k < 128) R = 64  + sl*64 + (k-64);       // hl-own
      else if (k < 192) R = 64  + ps*64 + (k-128);      // hl-partner
      else              R = 192 + sl*64 + (k-192);      // hr-own
      wr4[j] = *(const float4*)(W + (size_t)R*640 + gq);
      wr1[j] = W[(size_t)R*640 + gu];
    }
  }
  // --- W_ship^T into LDS: rows = my h-dims as partner's hr (192+sl*64..+64),
  //     cols = partner's 320 gate cols; stored [c][quad q^(c&15)] ---
  for (int idx = tid; idx < 320*16; idx += NTHR){
    const int c = idx >> 4, q = idx & 15;
    const int gc = (c < 256) ? ((c>>6)*128 + ps*64 + (c&63))
                             : (512 + ps*64 + (c-256));
    const int r0 = q*4;
    float4 v;
    v.x = W[(size_t)(192+sl*64+r0+0)*640 + gc];
    v.y = W[(size_t)(192+sl*64+r0+1)*640 + gc];
    v.z = W[(size_t)(192+sl*64+r0+2)*640 + gc];
    v.w = W[(size_t)(192+sl*64+r0+3)*640 + gc];
    wsq[c][q ^ (c&15)] = v;
  }
  if (tid < 320){
    const int c = tid;
    const int gc = (c < 256) ? ((c>>6)*128 + sl*64 + (c&63))
                             : (512 + sl*64 + (c-256));
    bsl[c] = bias[gc];
  }
  if (tid < HD) lshd[tid] = leaf[tid];
  if (tid < 2){   // precompute (mask, li); ri == t-1 always on a reduce
    int b = tid, p = 0;
    for (int t=0;t<D;++t){
      int m = trans[t*256 + gb0 + b];
      short li = 0;
      if (m) li = (short)stk_[b][p-2];
      mS[t][b] = (uint8_t)m; liA[t][b] = li;
      int np = p - 2*m; stk_[b][np] = (unsigned short)t; p = np+1;
    }
  }
  __syncthreads();

  // --- prefill xs[0] (mask(0)==0 by construction) ---
  for (int idx = tid; idx < 512; idx += NTHR){
    const int b = (idx >= 256) ? 1 : 0;
    const int r = idx - b*256;
    float v;
    if      (r < 64)  v = emb[(size_t)labels[gb0 + b]*LD + r];
    else if (r < 128) v = lshd[sl*64 + (r-64)];
    else if (r < 192) v = lshd[ps*64 + (r-128)];
    else              v = lshd[sl*64 + (r-192)];
    xs[0][b][r] = v;
  }
  __syncthreads();

  float ccprev = 0.f;   // own c[t-1][b][dl] (cell threads only)

  for (int t=0;t<D;++t){
    const int cur = t&1, nxt = cur^1;

    // ========== P1a: SHIP partial for partner (no dependency, stores fly) ==
    {
      const int b1 = (tid >= 320) ? 1 : 0;          // wave-uniform
      const int c1 = tid - b1*320;
      float a1 = 0.f;
#pragma unroll
      for (int q=0;q<16;++q){
        const float4 xq = *(const float4*)&xs[cur][b1][192+q*4];  // broadcast
        const float4 wq = wsq[c1][q ^ (c1&15)];
        a1 = __builtin_fmaf(wq.x,xq.x,__builtin_fmaf(wq.y,xq.y,
             __builtin_fmaf(wq.z,xq.z,__builtin_fmaf(wq.w,xq.w,a1))));
      }
      u64t* Pw = Pring + (((size_t)(t&3)*128 + g2)*2 + sl)*640;
      gst64r(Pw + tid, packw(a1, (unsigned)(t+1)));
      if (tid < 128){                               // words 512..639 (b=1)
        const int c2 = 192 + tid;
        float a2 = 0.f;
#pragma unroll
        for (int q=0;q<16;++q){
          const float4 xq = *(const float4*)&xs[cur][1][192+q*4];
          const float4 wq = wsq[c2][q ^ (c2&15)];
          a2 = __builtin_fmaf(wq.x,xq.x,__builtin_fmaf(wq.y,xq.y,
               __builtin_fmaf(wq.z,xq.z,__builtin_fmaf(wq.w,xq.w,a2))));
        }
        gst64r(Pw + 512 + tid, packw(a2, (unsigned)(t+1)));
      }
    }

    // ========== P1b: local GEMM, 256 K-rows, all 8 waves =================
    {
      float4 a0 = {0.f,0.f,0.f,0.f}, a1 = {0.f,0.f,0.f,0.f};
      float u0 = 0.f, u1 = 0.f;
#pragma unroll
      for (int j4=0;j4<8;++j4){
        const int k = kg*32 + j4*4;
        const float4 x0 = *(const float4*)&xs[cur][0][k];   // broadcast
        const float4 x1 = *(const float4*)&xs[cur][1][k];
        const float xa0[4] = {x0.x,x0.y,x0.z,x0.w};
        const float xa1[4] = {x1.x,x1.y,x1.z,x1.w};
#pragma unroll
        for (int jj=0;jj<4;++jj){
          const float4 w = wr4[j4*4+jj];
          const float wu = wr1[j4*4+jj];
          a0.x = __builtin_fmaf(w.x, xa0[jj], a0.x);
          a0.y = __builtin_fmaf(w.y, xa0[jj], a0.y);
          a0.z = __builtin_fmaf(w.z, xa0[jj], a0.z);
          a0.w = __builtin_fmaf(w.w, xa0[jj], a0.w);
          a1.x = __builtin_fmaf(w.x, xa1[jj], a1.x);
          a1.y = __builtin_fmaf(w.y, xa1[jj], a1.y);
          a1.z = __builtin_fmaf(w.z, xa1[jj], a1.z);
          a1.w = __builtin_fmaf(w.w, xa1[jj], a1.w);
          u0 = __builtin_fmaf(wu, xa0[jj], u0);
          u1 = __builtin_fmaf(wu, xa1[jj], u1);
        }
      }
      *(float4*)&gpq[kg*2+0][cq*4] = a0;
      *(float4*)&gpq[kg*2+1][cq*4] = a1;
      gpq[kg*2+0][256+cq] = u0;
      gpq[kg*2+1][256+cq] = u1;
    }
    __syncthreads();

    // ========== P2: cell (w0-1, +partial recv) || prefetch t+1 (w2,3,6) ===
    if (tid < 128){
      const int b = tid>>6, dl = tid&63, gd = sl*64+dl;
      const int m = mS[t][b];
      // issue partner-partial loads FIRST (sent at partner P1(t) start —
      // one full GEMM phase of flight already elapsed)
      const u64t* Pr = Pring + (((size_t)(t&3)*128 + g2)*2 + ps)*640;
      u64t pw[5];
#pragma unroll
      for (int g=0;g<4;++g) pw[g] = gld64r(Pr + b*320 + g*64 + dl);
      pw[4] = gld64r(Pr + b*320 + 256 + dl);
      // own-gate reduce meanwhile
      float s[5];
#pragma unroll
      for (int g=0; g<5; ++g){
        const int c = (g<4) ? (g*64+dl) : (256+dl);
        float a = 0.f;
#pragma unroll
        for (int kk=0; kk<8; ++kk) a += gpq[kk*2+b][c];
        s[g] = a + bsl[c];
      }
      // verify tags; retry if stale (expected first-try in steady state)
      const unsigned want = (unsigned)(t+1);
      int it = 0;
      while (!__all(((unsigned)(pw[0]>>32) == want) &
                    ((unsigned)(pw[1]>>32) == want) &
                    ((unsigned)(pw[2]>>32) == want) &
                    ((unsigned)(pw[3]>>32) == want) &
                    ((unsigned)(pw[4]>>32) == want))){
        __builtin_amdgcn_s_sleep(1);
#pragma unroll
        for (int g=0;g<4;++g) pw[g] = gld64r(Pr + b*320 + g*64 + dl);
        pw[4] = gld64r(Pr + b*320 + 256 + dl);
        if (++it > (1<<20)) break;   // safety: hang -> wrong answer
      }
#pragma unroll
      for (int g=0;g<5;++g) s[g] += loww(pw[g]);

      const float cl_ = m ? clb[cur][b][dl] : lshd[gd];
      const float cr_ = m ? ccprev : lshd[gd];      // ri == t-1: own prev c
      const float cc = sigf(s[0])*tanh_(s[4]) + sigf(s[1])*cl_ + sigf(s[2])*cr_;
      const float hh = sigf(s[3])*tanh_(cc);
      ccprev = cc;
      // publish tagged h (for partner's li==t-1 hl reads, one step later)
      gst64r(hring + (((size_t)(t&3)*128 + g2)*2 + sl)*128 + tid,
             packw(hh, (unsigned)(t+1)));
      const size_t ro = (((size_t)t*128 + g2)*2 + sl)*128 + b*64 + dl;
      gst32(rec + ro, hh);
      gst32(cown + ro, cc);
      if (t == D-1){
        out[(size_t)(gb0+b)*HD + gd] = cc;
        out[(size_t)256*HD + (size_t)(gb0+b)*HD + gd] = hh;
      } else {
        xs[nxt][b][192+dl] = mS[t+1][b] ? hh : lshd[gd];   // own hr for t+1
      }
      if (t+2 < D && mS[t+2][b] && liA[t+2][b] == t){
        xs[cur][b][64+dl] = hh;     // own hl for t+2 (li==t case)
        clb[cur][b][dl]   = cc;     // own cl for t+2
      }
    } else if (kg == 2){            // emb(t+1) -> label slots
      if (t+1 < D){
        const int b = lane>>5, jj = lane&31;
        const int row = labels[(t+1)*256 + gb0 + b];
        const float2 ev = *(const float2*)(emb + (size_t)row*LD + jj*2);
        xs[nxt][b][jj*2]   = ev.x;
        xs[nxt][b][jj*2+1] = ev.y;
      }
    } else if (kg == 3){            // own-half hl/cl for t+1
      if (t+1 < D){
        const int b = lane>>5, jj = lane&31;
        const int m1 = mS[t+1][b]; const int li = liA[t+1][b];
        if (m1){
          if (li <= t-2){
            const size_t ro = (((size_t)li*128+g2)*2 + sl)*128 + b*64 + jj*2;
            union{u64t u; float f[2];} h_, c_;
            h_.u = gld64(rec + ro);
            c_.u = gld64(cown + ro);
            xs[nxt][b][64+jj*2]   = h_.f[0];
            xs[nxt][b][64+jj*2+1] = h_.f[1];
            clb[nxt][b][jj*2]     = c_.f[0];
            clb[nxt][b][jj*2+1]   = c_.f[1];
          }
          // li == t-1: cell@t-1 already wrote xs/clb from registers
        } else {
          xs[nxt][b][64+jj*2]   = lshd[sl*64+jj*2];
          xs[nxt][b][64+jj*2+1] = lshd[sl*64+jj*2+1];
          clb[nxt][b][jj*2]     = lshd[sl*64+jj*2];
          clb[nxt][b][jj*2+1]   = lshd[sl*64+jj*2+1];
        }
      }
    } else if (kg == 6){            // partner-half hl for t+1
      if (t+1 < D){
        const int b = lane>>5, jj = lane&31;
        const int m1 = mS[t+1][b]; const int li = liA[t+1][b];
        if (m1){
          if (li <= t-2){
            const size_t ro = (((size_t)li*128+g2)*2 + ps)*128 + b*64 + jj*2;
            union{u64t u; float f[2];} h_;
            h_.u = gld64(rec + ro);
            xs[nxt][b][128+jj*2]   = h_.f[0];
            xs[nxt][b][128+jj*2+1] = h_.f[1];
          } else {                  // li == t-1: tagged h-ring spin-read
            const u64t* rp = hring + (((size_t)((t-1)&3)*128 + g2)*2 + ps)*128
                             + b*64 + jj*2;
            const unsigned want = (unsigned)t;   // tag = (t-1)+1
            u64t w0, w1; int it = 0;
            for (;;){
              w0 = gld64r(rp); w1 = gld64r(rp+1);
              if (__all(((unsigned)(w0>>32) == want) &
                        ((unsigned)(w1>>32) == want))) break;
              __builtin_amdgcn_s_sleep(1);
              if (++it > (1<<20)) break;
            }
            xs[nxt][b][128+jj*2]   = loww(w0);
            xs[nxt][b][128+jj*2+1] = loww(w1);
          }
        } else {
          xs[nxt][b][128+jj*2]   = lshd[ps*64+jj*2];
          xs[nxt][b][128+jj*2+1] = lshd[ps*64+jj*2+1];
        }
      }
    }
    __syncthreads();
  }
}

extern "C" void kernel_launch(void* const* d_in, const int* in_sizes, int n_in,
                              void* d_out, int out_size, void* d_ws, size_t ws_size,
                              hipStream_t stream) {
  (void)in_sizes; (void)n_in; (void)out_size; (void)ws_size;
  const int*   trans  = (const int*)d_in[0];
  const int*   labels = (const int*)d_in[1];
  const float* emb    = (const float*)d_in[2];
  const float* W      = (const float*)d_in[3];
  const float* bias   = (const float*)d_in[4];
  const float* leaf   = (const float*)d_in[5];
  float* out = (float*)d_out;

  // ws: [0, 5.25MB)  Pring: 4-deep self-tagged partial words
  //                  4 x 128 x 2 x 640 u64 (tag=t+1; poison/zero never match;
  //                  reuse distance 4, pair skew <=2 by dependency -> safe)
  //     [6MB, 7MB)   hring: 4-deep tagged h records, 4 x 128 x 2 x 128 u64
  //     [8MB, 72MB)  rec:  plain h records (li<=t-2 readers, >=2 steps old)
  //     [72MB,136MB) cown: plain c records (own-block readers only)
  uint8_t* ws = (uint8_t*)d_ws;
  u64t*  Pring = (u64t*)ws;
  u64t*  hring = (u64t*)(ws + ((size_t)6<<20));
  float* rec   = (float*)(ws + ((size_t)8<<20));
  float* cown  = (float*)(ws + ((size_t)72<<20));

  spinn_kernel<<<dim3(256), dim3(NTHR), 0, stream>>>(
      trans, labels, emb, W, bias, leaf, out, Pring, hring, rec, cown);
}